// Round 6
// baseline (263.463 us; speedup 1.0000x reference)
//
#include <hip/hip_runtime.h>
#include <hip/hip_bf16.h>

// Attn: energies = out_state @ (history @ W.T).T ; softmax rows.
// S2=S1=4096, N=1024. fp32 in/out. bf16 hi/lo GEMM, 3 products (Ah.Bh +
// Al.Bh + Ah.Bl), K=1024 per product, separate hi/lo arrays (R15: -33% bytes).
// R15 post-mortem: stage-2 was depth-1 / vmcnt(0) at EVERY boundary -- zero
// DMAs in flight across barriers (the R11/T4 lesson, regressed). m201 proves
// ~20 B/cyc/CU global_load_lds is reachable at 1 block/CU; we ran at 8.4.
// R16: half-slab ring. Stage-2 keeps 2x{Ah,Bh,Al,Bl} bufs (128 KB) but
// treats {Ah,Bh} / {Al,Bl} as independent staging units: unit0(t+1) issued
// in w0, unit1(t+1) in w1; vmcnt(4) at w1 and at boundary -> 4-8 loads in
// flight across EVERY barrier. Windows 5->3 (32 MFMA each), barriers 10->5
// per slab. Stage-1: NBUF=3 slabs (72 KB), depth-2, vmcnt(4) boundary,
// 2 windows (16+8 MFMA), barriers 6->3 per slab.

typedef __bf16 bf16x8 __attribute__((ext_vector_type(8)));
typedef float f32x4 __attribute__((ext_vector_type(4)));
typedef unsigned short u16x4 __attribute__((ext_vector_type(4)));

__device__ __forceinline__ unsigned short f2bf(float x) {
  unsigned int u = __float_as_uint(x);
  u += 0x7fffu + ((u >> 16) & 1u);   // RNE
  return (unsigned short)(u >> 16);
}
__device__ __forceinline__ float bf2f(unsigned short h) {
  return __uint_as_float(((unsigned int)h) << 16);
}

__device__ __forceinline__ void async_copy_16(void* lds, const void* gsrc) {
  __builtin_amdgcn_global_load_lds(
      (const __attribute__((address_space(1))) void*)gsrc,
      (__attribute__((address_space(3))) void*)lds, 16, 0, 0);
}

__device__ __forceinline__ void barrier_fenced() {
  asm volatile("" ::: "memory");
  __builtin_amdgcn_s_barrier();
  asm volatile("" ::: "memory");
}

// Split fp32 X[rows x 1024] -> Yh, Yl [rows x 1024] bf16 (hi + residual-lo).
__global__ __launch_bounds__(256)
void split_kernel(const float* __restrict__ X, unsigned short* __restrict__ Yh,
                  unsigned short* __restrict__ Yl) {
  const size_t row = blockIdx.x;
  const int c4 = threadIdx.x;
  float4 x = ((const float4*)(X + row * 1024))[c4];
  float xs[4] = {x.x, x.y, x.z, x.w};
  u16x4 h, l;
#pragma unroll
  for (int i = 0; i < 4; ++i) {
    unsigned short hh = f2bf(xs[i]);
    h[i] = hh;
    l[i] = f2bf(xs[i] - bf2f(hh));
  }
  ((u16x4*)(Yh + row * 1024))[c4] = h;
  ((u16x4*)(Yl + row * 1024))[c4] = l;
}

// C[M,N] = Ah.Bh^T + Al.Bh^T + Ah.Bl^T, K=1024, bf16 in fp32 acc.
// WM*WN waves, wave tile (BM/WM)x(BN/WN). Fragment-ordered LDS per 32-k
// slab: 16-row group g at byte g*1024 + lane*16 (lane = kseg*16+row) ==
// global_load_lds wave-uniform-base + lane*16; 2-way bank aliasing only.
// EPI=0: store fp32 C. EPI=1: store hi/lo split into Ph,Pl.
template <int BM, int BN, int WM, int WN, int NBUF, int EPI,
          int GM, int RM, int RN>
__global__ __launch_bounds__(WM * WN * 64, 2)
void gemm4(const unsigned short* __restrict__ Ah, const unsigned short* __restrict__ Al,
           const unsigned short* __restrict__ Bh, const unsigned short* __restrict__ Bl,
           float* __restrict__ C,
           unsigned short* __restrict__ Ph, unsigned short* __restrict__ Pl,
           int M, int N) {
  constexpr int NWAVE = WM * WN;
  constexpr int MT = BM / (WM * 16);     // m-frags per wave (8 or 4)
  constexpr int NT = BN / (WN * 16);     // n-frags per wave (4 or 2)
  constexpr int NA = (BM / 16) / NWAVE;  // chunks per wave per array (A-side)
  constexpr int NB = (BN / 16) / NWAVE;  // chunks per wave per array (B-side)
  constexpr int NTILES = 32;             // K = 1024, BK = 32
  __shared__ unsigned short AhS[NBUF][BM * 32];
  __shared__ unsigned short AlS[NBUF][BM * 32];
  __shared__ unsigned short BhS[NBUF][BN * 32];
  __shared__ unsigned short BlS[NBUF][BN * 32];

  const int tid = threadIdx.x;
  const int w = tid >> 6;
  const int lane = tid & 63;
  const int wm = w / WN, wn = w % WN;
  const int lr = lane & 15;
  const int ls = lane >> 4;

  // XCD-aware super-tile swizzle (grid = 256 = 8 XCDs x 32, bijective)
  const int id = blockIdx.x;
  const int xcd = id & 7;
  const int j = id >> 3;
  const int bm = ((xcd % (GM / RM)) * RM + (j % RM)) * BM;
  const int bn = ((xcd / (GM / RM)) * RN + (j / RM)) * BN;

  const unsigned short *pah[NA], *pal[NA];
#pragma unroll
  for (int c = 0; c < NA; ++c) {
    const size_t r = (size_t)(bm + (w * NA + c) * 16 + lr) * 1024 + ls * 8;
    pah[c] = Ah + r; pal[c] = Al + r;
  }
  const unsigned short *pbh[NB], *pbl[NB];
#pragma unroll
  for (int c = 0; c < NB; ++c) {
    const size_t r = (size_t)(bn + (w * NB + c) * 16 + lr) * 1024 + ls * 8;
    pbh[c] = Bh + r; pbl[c] = Bl + r;
  }

  f32x4 acc[MT][NT] = {};

  auto stageAh = [&](int buf, int t) {
#pragma unroll
    for (int c = 0; c < NA; ++c)
      async_copy_16(&AhS[buf][(w * NA + c) * 512], pah[c] + t * 32);
  };
  auto stageAl = [&](int buf, int t) {
#pragma unroll
    for (int c = 0; c < NA; ++c)
      async_copy_16(&AlS[buf][(w * NA + c) * 512], pal[c] + t * 32);
  };
  auto stageBh = [&](int buf, int t) {
#pragma unroll
    for (int c = 0; c < NB; ++c)
      async_copy_16(&BhS[buf][(w * NB + c) * 512], pbh[c] + t * 32);
  };
  auto stageBl = [&](int buf, int t) {
#pragma unroll
    for (int c = 0; c < NB; ++c)
      async_copy_16(&BlS[buf][(w * NB + c) * 512], pbl[c] + t * 32);
  };

  auto LDAh = [&](int buf, int g) { return *(const bf16x8*)&AhS[buf][g * 512 + ls * 128 + lr * 8]; };
  auto LDAl = [&](int buf, int g) { return *(const bf16x8*)&AlS[buf][g * 512 + ls * 128 + lr * 8]; };
  auto LDBh = [&](int buf, int g) { return *(const bf16x8*)&BhS[buf][g * 512 + ls * 128 + lr * 8]; };
  auto LDBl = [&](int buf, int g) { return *(const bf16x8*)&BlS[buf][g * 512 + ls * 128 + lr * 8]; };

  if constexpr (MT == 8) {
    // ================= stage-2: 256x256, NBUF=2, half-slab ring ==========
    // units: u0 = {Ah,Bh} (4 loads/wave), u1 = {Al,Bl} (4 loads/wave).
    // u0(t+1) issued at w0, u1(t+1) at w1. vmcnt(4) at w1 (drain u1(t),
    // keep u0(t+1)) and at boundary (drain u0(t+1), keep u1(t+1)).
    // prologue: u0(0), u1(0); drain u0(0) only.
    stageAh(0, 0); stageBh(0, 0);
    stageAl(0, 0); stageBl(0, 0);
    asm volatile("s_waitcnt vmcnt(4)" ::: "memory");
    barrier_fenced();

#pragma unroll 1
    for (int t = 0; t < NTILES; ++t) {
      const int buf = t & 1, nb = (t + 1) & 1;
      const bool st = (t + 1 < NTILES);
      bf16x8 ah[8], bh[4], bl[4], al[8];

      // ---- w0: Ah,Bh reads; issue u0(t+1); 32 MFMA Ah.Bh ----
#pragma unroll
      for (int mt = 0; mt < 8; ++mt) ah[mt] = LDAh(buf, wm * MT + mt);
#pragma unroll
      for (int nt = 0; nt < 4; ++nt) bh[nt] = LDBh(buf, wn * NT + nt);
      if (st) { stageAh(nb, t + 1); stageBh(nb, t + 1); }
      barrier_fenced();
      asm volatile("s_waitcnt lgkmcnt(0)" ::: "memory");
      __builtin_amdgcn_sched_barrier(0);
      __builtin_amdgcn_s_setprio(1);
#pragma unroll
      for (int mt = 0; mt < 8; ++mt)
#pragma unroll
        for (int nt = 0; nt < 4; ++nt)
          acc[mt][nt] = __builtin_amdgcn_mfma_f32_16x16x32_bf16(ah[mt], bh[nt], acc[mt][nt], 0, 0, 0);
      __builtin_amdgcn_s_setprio(0);
      __builtin_amdgcn_sched_barrier(0);

      // ---- w1: drain u1(t); Bl reads; issue u1(t+1); 32 MFMA Ah.Bl ----
      if (st) asm volatile("s_waitcnt vmcnt(4)" ::: "memory");
      else    asm volatile("s_waitcnt vmcnt(0)" ::: "memory");
      barrier_fenced();
#pragma unroll
      for (int nt = 0; nt < 4; ++nt) bl[nt] = LDBl(buf, wn * NT + nt);
      if (st) { stageAl(nb, t + 1); stageBl(nb, t + 1); }
      barrier_fenced();
      asm volatile("s_waitcnt lgkmcnt(0)" ::: "memory");
      __builtin_amdgcn_sched_barrier(0);
      __builtin_amdgcn_s_setprio(1);
#pragma unroll
      for (int mt = 0; mt < 8; ++mt)
#pragma unroll
        for (int nt = 0; nt < 4; ++nt)
          acc[mt][nt] = __builtin_amdgcn_mfma_f32_16x16x32_bf16(ah[mt], bl[nt], acc[mt][nt], 0, 0, 0);
      __builtin_amdgcn_s_setprio(0);
      __builtin_amdgcn_sched_barrier(0);

      // ---- w2: Al reads; 32 MFMA Al.Bh ----
#pragma unroll
      for (int mt = 0; mt < 8; ++mt) al[mt] = LDAl(buf, wm * MT + mt);
      barrier_fenced();
      asm volatile("s_waitcnt lgkmcnt(0)" ::: "memory");
      __builtin_amdgcn_sched_barrier(0);
      __builtin_amdgcn_s_setprio(1);
#pragma unroll
      for (int mt = 0; mt < 8; ++mt)
#pragma unroll
        for (int nt = 0; nt < 4; ++nt)
          acc[mt][nt] = __builtin_amdgcn_mfma_f32_16x16x32_bf16(al[mt], bh[nt], acc[mt][nt], 0, 0, 0);
      __builtin_amdgcn_s_setprio(0);
      __builtin_amdgcn_sched_barrier(0);

      // ---- boundary: drain u0(t+1), keep u1(t+1) in flight ----
      if (st) asm volatile("s_waitcnt vmcnt(4)" ::: "memory");
      else    asm volatile("s_waitcnt vmcnt(0)" ::: "memory");
      barrier_fenced();
    }
  } else {
    // ================= stage-1: 128x128, NBUF=3, depth-2 =================
    // all 4 arrays of slab t+2 issued at w0 (4 loads/wave); boundary
    // vmcnt(4) drains slab t+1's, keeps t+2's in flight.
    stageAh(0, 0); stageBh(0, 0); stageAl(0, 0); stageBl(0, 0);
    stageAh(1, 1); stageBh(1, 1); stageAl(1, 1); stageBl(1, 1);
    asm volatile("s_waitcnt vmcnt(4)" ::: "memory");
    barrier_fenced();

#pragma unroll 1
    for (int t = 0; t < NTILES; ++t) {
      const int buf = t % 3, nb = (t + 2) % 3;
      const bool st = (t + 2 < NTILES);
      bf16x8 ah[4], bh[2], bl[2], al[4];

      // ---- w0: Ah,Bh,Bl reads; issue slab t+2; 16 MFMA (Ah.Bh, Ah.Bl) ----
#pragma unroll
      for (int mt = 0; mt < 4; ++mt) ah[mt] = LDAh(buf, wm * MT + mt);
#pragma unroll
      for (int nt = 0; nt < 2; ++nt) bh[nt] = LDBh(buf, wn * NT + nt);
#pragma unroll
      for (int nt = 0; nt < 2; ++nt) bl[nt] = LDBl(buf, wn * NT + nt);
      if (st) { stageAh(nb, t + 2); stageBh(nb, t + 2); stageAl(nb, t + 2); stageBl(nb, t + 2); }
      barrier_fenced();
      asm volatile("s_waitcnt lgkmcnt(0)" ::: "memory");
      __builtin_amdgcn_sched_barrier(0);
      __builtin_amdgcn_s_setprio(1);
#pragma unroll
      for (int mt = 0; mt < 4; ++mt)
#pragma unroll
        for (int nt = 0; nt < 2; ++nt)
          acc[mt][nt] = __builtin_amdgcn_mfma_f32_16x16x32_bf16(ah[mt], bh[nt], acc[mt][nt], 0, 0, 0);
#pragma unroll
      for (int mt = 0; mt < 4; ++mt)
#pragma unroll
        for (int nt = 0; nt < 2; ++nt)
          acc[mt][nt] = __builtin_amdgcn_mfma_f32_16x16x32_bf16(ah[mt], bl[nt], acc[mt][nt], 0, 0, 0);
      __builtin_amdgcn_s_setprio(0);
      __builtin_amdgcn_sched_barrier(0);

      // ---- w1: Al reads; 8 MFMA (Al.Bh) ----
#pragma unroll
      for (int mt = 0; mt < 4; ++mt) al[mt] = LDAl(buf, wm * MT + mt);
      barrier_fenced();
      asm volatile("s_waitcnt lgkmcnt(0)" ::: "memory");
      __builtin_amdgcn_sched_barrier(0);
      __builtin_amdgcn_s_setprio(1);
#pragma unroll
      for (int mt = 0; mt < 4; ++mt)
#pragma unroll
        for (int nt = 0; nt < 2; ++nt)
          acc[mt][nt] = __builtin_amdgcn_mfma_f32_16x16x32_bf16(al[mt], bh[nt], acc[mt][nt], 0, 0, 0);
      __builtin_amdgcn_s_setprio(0);
      __builtin_amdgcn_sched_barrier(0);

      // ---- boundary: drain slab t+1, keep t+2 in flight ----
      if (st) asm volatile("s_waitcnt vmcnt(4)" ::: "memory");
      else    asm volatile("s_waitcnt vmcnt(0)" ::: "memory");
      barrier_fenced();
    }
  }

  // Epilogue. C/D layout (m89/m91): col(n) = lane&15, row(m) = (lane>>4)*4 + reg.
  const int cm0 = bm + wm * (BM / WM);
  const int cn0 = bn + wn * (BN / WN);
#pragma unroll
  for (int mt = 0; mt < MT; ++mt) {
#pragma unroll
    for (int nt = 0; nt < NT; ++nt) {
      const int col = cn0 + nt * 16 + lr;
      const int row0 = cm0 + mt * 16 + ls * 4;
      if constexpr (EPI == 0) {
#pragma unroll
        for (int r = 0; r < 4; ++r)
          C[(size_t)(row0 + r) * N + col] = acc[mt][nt][r];
      } else {
#pragma unroll
        for (int r = 0; r < 4; ++r) {
          const float p = acc[mt][nt][r];
          const unsigned short h = f2bf(p);
          const unsigned short l = f2bf(p - bf2f(h));
          const size_t base = (size_t)(row0 + r) * 1024 + col;
          Ph[base] = h;
          Pl[base] = l;
        }
      }
    }
  }
}

// In-place row softmax, N=4096, one block per row, 16 floats/thread in regs.
__global__ __launch_bounds__(256)
void softmax_inplace(float* __restrict__ C, int N) {
  float4* r4 = (float4*)(C + (size_t)blockIdx.x * N);
  const int t = threadIdx.x;
  float4 v[4];
  float mx = -3.0e38f;
#pragma unroll
  for (int i = 0; i < 4; ++i) {
    v[i] = r4[t + i * 256];
    mx = fmaxf(mx, fmaxf(fmaxf(v[i].x, v[i].y), fmaxf(v[i].z, v[i].w)));
  }
#pragma unroll
  for (int o = 32; o; o >>= 1) mx = fmaxf(mx, __shfl_xor(mx, o, 64));
  __shared__ float smax[4], ssum[4];
  const int w = t >> 6;
  if ((t & 63) == 0) smax[w] = mx;
  __syncthreads();
  mx = fmaxf(fmaxf(smax[0], smax[1]), fmaxf(smax[2], smax[3]));
  float s = 0.f;
#pragma unroll
  for (int i = 0; i < 4; ++i) {
    v[i].x = __expf(v[i].x - mx);
    v[i].y = __expf(v[i].y - mx);
    v[i].z = __expf(v[i].z - mx);
    v[i].w = __expf(v[i].w - mx);
    s += (v[i].x + v[i].y) + (v[i].z + v[i].w);
  }
#pragma unroll
  for (int o = 32; o; o >>= 1) s += __shfl_xor(s, o, 64);
  if ((t & 63) == 0) ssum[w] = s;
  __syncthreads();
  const float inv = 1.0f / (ssum[0] + ssum[1] + ssum[2] + ssum[3]);
#pragma unroll
  for (int i = 0; i < 4; ++i) {
    v[i].x *= inv; v[i].y *= inv; v[i].z *= inv; v[i].w *= inv;
    r4[t + i * 256] = v[i];
  }
}

extern "C" void kernel_launch(void* const* d_in, const int* in_sizes, int n_in,
                              void* d_out, int out_size, void* d_ws, size_t ws_size,
                              hipStream_t stream) {
  const float* out_state = (const float*)d_in[0];  // [4096,1024]
  const float* history   = (const float*)d_in[1];  // [4096,1024]
  const float* W         = (const float*)d_in[2];  // [1024,1024]
  float* out = (float*)d_out;                      // [4096,4096]

  unsigned short* Hh = (unsigned short*)d_ws;                 // 4096x1024 each
  unsigned short* Hl = Hh + (size_t)4096 * 1024;
  unsigned short* Wh = Hl + (size_t)4096 * 1024;              // 1024x1024
  unsigned short* Wl = Wh + (size_t)1024 * 1024;
  unsigned short* Ah = Wl + (size_t)1024 * 1024;              // 4096x1024
  unsigned short* Al = Ah + (size_t)4096 * 1024;
  unsigned short* Ph = Al + (size_t)4096 * 1024;              // 4096x1024
  unsigned short* Pl = Ph + (size_t)4096 * 1024;

  split_kernel<<<4096, 256, 0, stream>>>(history, Hh, Hl);
  split_kernel<<<1024, 256, 0, stream>>>(W, Wh, Wl);
  split_kernel<<<4096, 256, 0, stream>>>(out_state, Ah, Al);

  // proj -> Ph,Pl. 128x128, 8 waves, NBUF=3 (72 KB), depth-2 counted vmcnt,
  // 2 windows (16+8 MFMA), 3 barriers/slab, 32 slabs. Grid 32x8 = 256.
  gemm4<128, 128, 2, 4, 3, 1, 32, 8, 4><<<256, 512, 0, stream>>>(
      Hh, Hl, Wh, Wl, nullptr, Ph, Pl, 4096, 1024);

  // energies -> d_out. 256x256, 8 waves, NBUF=2 (128 KB) half-slab ring:
  // u0={Ah,Bh}, u1={Al,Bl}; 4-8 loads in flight across every barrier,
  // 3 windows x 32 MFMA, 5 barriers/slab, 32 slabs. Grid 16x16 = 256.
  gemm4<256, 256, 2, 4, 2, 0, 16, 4, 8><<<256, 512, 0, stream>>>(
      Ah, Al, Ph, Pl, out, nullptr, nullptr, 4096, 4096);

  softmax_inplace<<<4096, 256, 0, stream>>>(out, 4096);
}

// Round 7
// 253.723 us; speedup vs baseline: 1.0384x; 1.0384x over previous
//
#include <hip/hip_runtime.h>
#include <hip/hip_bf16.h>

// Attn: energies = out_state @ (history @ W.T).T ; softmax rows.
// S2=S1=4096, N=1024. fp32 in/out. bf16 hi/lo GEMM, 3 products
// (Ah.Bh + Al.Bh + Ah.Bl), separate hi/lo arrays (R15: -33% staged bytes).
// R15: stage-2 5-window lockstep, NBUF=2 depth-1: 104.5 us -- measured at
//      >=94% of the 2-wave/SIMD MFMA-issue floor. KEEP (reverted from R16).
// R16: half-slab ring: regression (112.8). Reverted.
// R17: stage-1 is a fixed ~3000-cyc/slab lockstep slot regardless of
//      schedule (R12/R14/R15/R16 all ~100 us for 25.8 GFLOP). Fix is NOT
//      another schedule: fill the slot with a SECOND resident block (m114
//      cross-block overlap). Split-K: 512 blocks (2 K-halves x 256 tiles),
//      NBUF=2 -> 64 KB LDS -> 2 blocks/CU; fp32 partials + reduce_split
//      kernel (Pa+Pb -> Ph,Pl, ~9 us). Kernels renamed gemm_e / gemm_p for
//      rocprof visibility.

typedef __bf16 bf16x8 __attribute__((ext_vector_type(8)));
typedef float f32x4 __attribute__((ext_vector_type(4)));
typedef unsigned short u16x4 __attribute__((ext_vector_type(4)));

__device__ __forceinline__ unsigned short f2bf(float x) {
  unsigned int u = __float_as_uint(x);
  u += 0x7fffu + ((u >> 16) & 1u);   // RNE
  return (unsigned short)(u >> 16);
}
__device__ __forceinline__ float bf2f(unsigned short h) {
  return __uint_as_float(((unsigned int)h) << 16);
}

__device__ __forceinline__ void async_copy_16(void* lds, const void* gsrc) {
  __builtin_amdgcn_global_load_lds(
      (const __attribute__((address_space(1))) void*)gsrc,
      (__attribute__((address_space(3))) void*)lds, 16, 0, 0);
}

__device__ __forceinline__ void barrier_fenced() {
  asm volatile("" ::: "memory");
  __builtin_amdgcn_s_barrier();
  asm volatile("" ::: "memory");
}

// Split fp32 X[rows x 1024] -> Yh, Yl [rows x 1024] bf16 (hi + residual-lo).
__global__ __launch_bounds__(256)
void split_kernel(const float* __restrict__ X, unsigned short* __restrict__ Yh,
                  unsigned short* __restrict__ Yl) {
  const size_t row = blockIdx.x;
  const int c4 = threadIdx.x;
  float4 x = ((const float4*)(X + row * 1024))[c4];
  float xs[4] = {x.x, x.y, x.z, x.w};
  u16x4 h, l;
#pragma unroll
  for (int i = 0; i < 4; ++i) {
    unsigned short hh = f2bf(xs[i]);
    h[i] = hh;
    l[i] = f2bf(xs[i] - bf2f(hh));
  }
  ((u16x4*)(Yh + row * 1024))[c4] = h;
  ((u16x4*)(Yl + row * 1024))[c4] = l;
}

// ============================ stage-2: energies =============================
// C[4096,4096] = Ah.Bh^T + Al.Bh^T + Ah.Bl^T, K=1024. 256x256 tile, 8 waves
// (2x4), wave tile 128x64. NBUF=2 depth-1, 5 lockstep windows/slab (R15).
// Fragment-ordered LDS: 16-row group g at byte g*1024 + lane*16; matches
// global_load_lds wave-uniform-base + lane*16; 2-way bank alias only.
__global__ __launch_bounds__(512, 2)
void gemm_e(const unsigned short* __restrict__ Ah, const unsigned short* __restrict__ Al,
            const unsigned short* __restrict__ Bh, const unsigned short* __restrict__ Bl,
            float* __restrict__ C) {
  constexpr int MT = 8, NT = 4, NA = 2, NB = 2, NTILES = 32;
  __shared__ unsigned short AhS[2][256 * 32];
  __shared__ unsigned short AlS[2][256 * 32];
  __shared__ unsigned short BhS[2][256 * 32];
  __shared__ unsigned short BlS[2][256 * 32];

  const int tid = threadIdx.x;
  const int w = tid >> 6;
  const int lane = tid & 63;
  const int wm = w >> 2, wn = w & 3;
  const int lr = lane & 15;
  const int ls = lane >> 4;

  // XCD swizzle: grid 256 = 8 XCDs x 32; GM=16, RM=4, RN=8 (bijective)
  const int id = blockIdx.x;
  const int xcd = id & 7;
  const int j = id >> 3;
  const int bm = ((xcd % 4) * 4 + (j % 4)) * 256;
  const int bn = ((xcd / 4) * 8 + (j / 4)) * 256;

  const unsigned short *pah[NA], *pal[NA];
#pragma unroll
  for (int c = 0; c < NA; ++c) {
    const size_t r = (size_t)(bm + (w * NA + c) * 16 + lr) * 1024 + ls * 8;
    pah[c] = Ah + r; pal[c] = Al + r;
  }
  const unsigned short *pbh[NB], *pbl[NB];
#pragma unroll
  for (int c = 0; c < NB; ++c) {
    const size_t r = (size_t)(bn + (w * NB + c) * 16 + lr) * 1024 + ls * 8;
    pbh[c] = Bh + r; pbl[c] = Bl + r;
  }

  f32x4 acc[MT][NT] = {};

  auto stageAh = [&](int buf, int t) {
#pragma unroll
    for (int c = 0; c < NA; ++c)
      async_copy_16(&AhS[buf][(w * NA + c) * 512], pah[c] + t * 32);
  };
  auto stageAl = [&](int buf, int t) {
#pragma unroll
    for (int c = 0; c < NA; ++c)
      async_copy_16(&AlS[buf][(w * NA + c) * 512], pal[c] + t * 32);
  };
  auto stageBh = [&](int buf, int t) {
#pragma unroll
    for (int c = 0; c < NB; ++c)
      async_copy_16(&BhS[buf][(w * NB + c) * 512], pbh[c] + t * 32);
  };
  auto stageBl = [&](int buf, int t) {
#pragma unroll
    for (int c = 0; c < NB; ++c)
      async_copy_16(&BlS[buf][(w * NB + c) * 512], pbl[c] + t * 32);
  };
  auto LDAh = [&](int buf, int g) { return *(const bf16x8*)&AhS[buf][g * 512 + ls * 128 + lr * 8]; };
  auto LDAl = [&](int buf, int g) { return *(const bf16x8*)&AlS[buf][g * 512 + ls * 128 + lr * 8]; };
  auto LDBh = [&](int buf, int g) { return *(const bf16x8*)&BhS[buf][g * 512 + ls * 128 + lr * 8]; };
  auto LDBl = [&](int buf, int g) { return *(const bf16x8*)&BlS[buf][g * 512 + ls * 128 + lr * 8]; };

  stageAh(0, 0); stageAl(0, 0); stageBh(0, 0); stageBl(0, 0);
  asm volatile("s_waitcnt vmcnt(0)" ::: "memory");
  barrier_fenced();

#pragma unroll 1
  for (int t = 0; t < NTILES; ++t) {
    const int buf = t & 1, nb = buf ^ 1;
    const bool st = (t + 1 < NTILES);
    bf16x8 ah[8], al[8], bh[4], bl[4];

    // ph0: Ah[0..4) + Bh reads; issue Ah(t+1); 16 MFMA
#pragma unroll
    for (int mt = 0; mt < 4; ++mt) ah[mt] = LDAh(buf, wm * MT + mt);
#pragma unroll
    for (int nt = 0; nt < 4; ++nt) bh[nt] = LDBh(buf, wn * NT + nt);
    if (st) stageAh(nb, t + 1);
    barrier_fenced();
    asm volatile("s_waitcnt lgkmcnt(0)" ::: "memory");
    __builtin_amdgcn_sched_barrier(0);
    __builtin_amdgcn_s_setprio(1);
#pragma unroll
    for (int mt = 0; mt < 4; ++mt)
#pragma unroll
      for (int nt = 0; nt < 4; ++nt)
        acc[mt][nt] = __builtin_amdgcn_mfma_f32_16x16x32_bf16(ah[mt], bh[nt], acc[mt][nt], 0, 0, 0);
    __builtin_amdgcn_s_setprio(0);
    __builtin_amdgcn_sched_barrier(0);

    // ph1: Ah[4..8); issue Bh(t+1); 16 MFMA
    barrier_fenced();
#pragma unroll
    for (int mt = 4; mt < 8; ++mt) ah[mt] = LDAh(buf, wm * MT + mt);
    if (st) stageBh(nb, t + 1);
    barrier_fenced();
    asm volatile("s_waitcnt lgkmcnt(0)" ::: "memory");
    __builtin_amdgcn_sched_barrier(0);
    __builtin_amdgcn_s_setprio(1);
#pragma unroll
    for (int mt = 4; mt < 8; ++mt)
#pragma unroll
      for (int nt = 0; nt < 4; ++nt)
        acc[mt][nt] = __builtin_amdgcn_mfma_f32_16x16x32_bf16(ah[mt], bh[nt], acc[mt][nt], 0, 0, 0);
    __builtin_amdgcn_s_setprio(0);
    __builtin_amdgcn_sched_barrier(0);

    // ph2: Bl; issue Al(t+1); 16 MFMA (ah[0..4) x bl)
    barrier_fenced();
#pragma unroll
    for (int nt = 0; nt < 4; ++nt) bl[nt] = LDBl(buf, wn * NT + nt);
    if (st) stageAl(nb, t + 1);
    barrier_fenced();
    asm volatile("s_waitcnt lgkmcnt(0)" ::: "memory");
    __builtin_amdgcn_sched_barrier(0);
    __builtin_amdgcn_s_setprio(1);
#pragma unroll
    for (int mt = 0; mt < 4; ++mt)
#pragma unroll
      for (int nt = 0; nt < 4; ++nt)
        acc[mt][nt] = __builtin_amdgcn_mfma_f32_16x16x32_bf16(ah[mt], bl[nt], acc[mt][nt], 0, 0, 0);
    __builtin_amdgcn_s_setprio(0);
    __builtin_amdgcn_sched_barrier(0);

    // ph3: Al[0..4); issue Bl(t+1); 16 MFMA (ah[4..8) x bl)
    barrier_fenced();
#pragma unroll
    for (int mt = 0; mt < 4; ++mt) al[mt] = LDAl(buf, wm * MT + mt);
    if (st) stageBl(nb, t + 1);
    barrier_fenced();
    asm volatile("s_waitcnt lgkmcnt(0)" ::: "memory");
    __builtin_amdgcn_sched_barrier(0);
    __builtin_amdgcn_s_setprio(1);
#pragma unroll
    for (int mt = 4; mt < 8; ++mt)
#pragma unroll
      for (int nt = 0; nt < 4; ++nt)
        acc[mt][nt] = __builtin_amdgcn_mfma_f32_16x16x32_bf16(ah[mt], bl[nt], acc[mt][nt], 0, 0, 0);
    __builtin_amdgcn_s_setprio(0);
    __builtin_amdgcn_sched_barrier(0);

    // ph4: Al[4..8); 32 MFMA (al x bh)
    barrier_fenced();
#pragma unroll
    for (int mt = 4; mt < 8; ++mt) al[mt] = LDAl(buf, wm * MT + mt);
    barrier_fenced();
    asm volatile("s_waitcnt lgkmcnt(0)" ::: "memory");
    __builtin_amdgcn_sched_barrier(0);
    __builtin_amdgcn_s_setprio(1);
#pragma unroll
    for (int mt = 0; mt < 8; ++mt)
#pragma unroll
      for (int nt = 0; nt < 4; ++nt)
        acc[mt][nt] = __builtin_amdgcn_mfma_f32_16x16x32_bf16(al[mt], bh[nt], acc[mt][nt], 0, 0, 0);
    __builtin_amdgcn_s_setprio(0);
    __builtin_amdgcn_sched_barrier(0);

    // boundary: drain slab t+1's DMAs, publish
    __builtin_amdgcn_sched_barrier(0);
    asm volatile("s_waitcnt vmcnt(0)" ::: "memory");
    barrier_fenced();
  }

  // Epilogue. C/D layout: col = lane&15, row = (lane>>4)*4 + reg.
  const int cm0 = bm + wm * 128;
  const int cn0 = bn + wn * 64;
#pragma unroll
  for (int mt = 0; mt < MT; ++mt)
#pragma unroll
    for (int nt = 0; nt < NT; ++nt) {
      const int col = cn0 + nt * 16 + lr;
      const int row0 = cm0 + mt * 16 + ls * 4;
#pragma unroll
      for (int r = 0; r < 4; ++r)
        C[(size_t)(row0 + r) * 4096 + col] = acc[mt][nt][r];
    }
}

// ============================ stage-1: proj (split-K) =======================
// Cpart[kh][4096,1024] = partial over K-half kh of Ah.Bh + Al.Bh + Ah.Bl.
// 128x128 tile, 8 waves (2x4), wave tile 64x32. NBUF=2 -> 64 KB LDS ->
// 2 blocks/CU: cross-block overlap fills the lockstep slot. 16 slabs.
__global__ __launch_bounds__(512, 2)
void gemm_p(const unsigned short* __restrict__ Ah, const unsigned short* __restrict__ Al,
            const unsigned short* __restrict__ Bh, const unsigned short* __restrict__ Bl,
            float* __restrict__ Cpart) {
  constexpr int MT = 4, NT = 2, NTILES = 16;
  __shared__ unsigned short AhS[2][128 * 32];
  __shared__ unsigned short AlS[2][128 * 32];
  __shared__ unsigned short BhS[2][128 * 32];
  __shared__ unsigned short BlS[2][128 * 32];

  const int tid = threadIdx.x;
  const int w = tid >> 6;
  const int lane = tid & 63;
  const int wm = w >> 2, wn = w & 3;
  const int lr = lane & 15;
  const int ls = lane >> 4;

  // grid 512 = 2 K-halves x 256 tiles; tile part XCD-swizzled (GM=32,RM=8,RN=4)
  const int kh = blockIdx.x >> 8;
  const int rid = blockIdx.x & 255;
  const int xcd = rid & 7;
  const int j = rid >> 3;
  const int bm = ((xcd % 4) * 8 + (j % 8)) * 128;
  const int bn = ((xcd / 4) * 4 + (j / 8)) * 128;
  const int koff = kh * 512;
  float* __restrict__ C = Cpart + (size_t)kh * 4096 * 1024;

  const unsigned short *pah, *pal, *pbh, *pbl;
  {
    const size_t ra = (size_t)(bm + w * 16 + lr) * 1024 + koff + ls * 8;
    pah = Ah + ra; pal = Al + ra;
    const size_t rb = (size_t)(bn + w * 16 + lr) * 1024 + koff + ls * 8;
    pbh = Bh + rb; pbl = Bl + rb;
  }

  f32x4 acc[MT][NT] = {};

  auto stage_all = [&](int buf, int t) {
    async_copy_16(&AhS[buf][w * 512], pah + t * 32);
    async_copy_16(&BhS[buf][w * 512], pbh + t * 32);
    async_copy_16(&BlS[buf][w * 512], pbl + t * 32);
    async_copy_16(&AlS[buf][w * 512], pal + t * 32);
  };
  auto LDAh = [&](int buf, int g) { return *(const bf16x8*)&AhS[buf][g * 512 + ls * 128 + lr * 8]; };
  auto LDAl = [&](int buf, int g) { return *(const bf16x8*)&AlS[buf][g * 512 + ls * 128 + lr * 8]; };
  auto LDBh = [&](int buf, int g) { return *(const bf16x8*)&BhS[buf][g * 512 + ls * 128 + lr * 8]; };
  auto LDBl = [&](int buf, int g) { return *(const bf16x8*)&BlS[buf][g * 512 + ls * 128 + lr * 8]; };

  stage_all(0, 0);
  asm volatile("s_waitcnt vmcnt(0)" ::: "memory");
  barrier_fenced();

#pragma unroll 1
  for (int t = 0; t < NTILES; ++t) {
    const int buf = t & 1, nb = buf ^ 1;
    const bool st = (t + 1 < NTILES);
    bf16x8 ah[4], al[4], bh[2], bl[2];

    // w0: Ah,Bh,Bl reads; issue slab t+1; 16 MFMA (ah.bh + ah.bl)
#pragma unroll
    for (int mt = 0; mt < 4; ++mt) ah[mt] = LDAh(buf, wm * MT + mt);
#pragma unroll
    for (int nt = 0; nt < 2; ++nt) bh[nt] = LDBh(buf, wn * NT + nt);
#pragma unroll
    for (int nt = 0; nt < 2; ++nt) bl[nt] = LDBl(buf, wn * NT + nt);
    if (st) stage_all(nb, t + 1);
    barrier_fenced();
    asm volatile("s_waitcnt lgkmcnt(0)" ::: "memory");
    __builtin_amdgcn_sched_barrier(0);
    __builtin_amdgcn_s_setprio(1);
#pragma unroll
    for (int mt = 0; mt < 4; ++mt)
#pragma unroll
      for (int nt = 0; nt < 2; ++nt)
        acc[mt][nt] = __builtin_amdgcn_mfma_f32_16x16x32_bf16(ah[mt], bh[nt], acc[mt][nt], 0, 0, 0);
#pragma unroll
    for (int mt = 0; mt < 4; ++mt)
#pragma unroll
      for (int nt = 0; nt < 2; ++nt)
        acc[mt][nt] = __builtin_amdgcn_mfma_f32_16x16x32_bf16(ah[mt], bl[nt], acc[mt][nt], 0, 0, 0);
    __builtin_amdgcn_s_setprio(0);
    __builtin_amdgcn_sched_barrier(0);

    // w1: Al reads; 8 MFMA (al.bh)
#pragma unroll
    for (int mt = 0; mt < 4; ++mt) al[mt] = LDAl(buf, wm * MT + mt);
    barrier_fenced();
    asm volatile("s_waitcnt lgkmcnt(0)" ::: "memory");
    __builtin_amdgcn_sched_barrier(0);
    __builtin_amdgcn_s_setprio(1);
#pragma unroll
    for (int mt = 0; mt < 4; ++mt)
#pragma unroll
      for (int nt = 0; nt < 2; ++nt)
        acc[mt][nt] = __builtin_amdgcn_mfma_f32_16x16x32_bf16(al[mt], bh[nt], acc[mt][nt], 0, 0, 0);
    __builtin_amdgcn_s_setprio(0);
    __builtin_amdgcn_sched_barrier(0);

    // boundary: drain slab t+1's DMAs (cross-block overlap hides this)
    __builtin_amdgcn_sched_barrier(0);
    asm volatile("s_waitcnt vmcnt(0)" ::: "memory");
    barrier_fenced();
  }

  // Epilogue: fp32 partial write.
  const int cm0 = bm + wm * 64;
  const int cn0 = bn + wn * 32;
#pragma unroll
  for (int mt = 0; mt < MT; ++mt)
#pragma unroll
    for (int nt = 0; nt < NT; ++nt) {
      const int col = cn0 + nt * 16 + lr;
      const int row0 = cm0 + mt * 16 + ls * 4;
#pragma unroll
      for (int r = 0; r < 4; ++r)
        C[(size_t)(row0 + r) * 1024 + col] = acc[mt][nt][r];
    }
}

// P = Pa + Pb; split hi/lo into Ph, Pl. Row per block.
__global__ __launch_bounds__(256)
void reduce_split(const float* __restrict__ Pa, const float* __restrict__ Pb,
                  unsigned short* __restrict__ Ph, unsigned short* __restrict__ Pl) {
  const size_t row = blockIdx.x;
  const int c4 = threadIdx.x;
  float4 a = ((const float4*)(Pa + row * 1024))[c4];
  float4 b = ((const float4*)(Pb + row * 1024))[c4];
  float s[4] = {a.x + b.x, a.y + b.y, a.z + b.z, a.w + b.w};
  u16x4 h, l;
#pragma unroll
  for (int i = 0; i < 4; ++i) {
    unsigned short hh = f2bf(s[i]);
    h[i] = hh;
    l[i] = f2bf(s[i] - bf2f(hh));
  }
  ((u16x4*)(Ph + row * 1024))[c4] = h;
  ((u16x4*)(Pl + row * 1024))[c4] = l;
}

// In-place row softmax, N=4096, one block per row, 16 floats/thread in regs.
__global__ __launch_bounds__(256)
void softmax_inplace(float* __restrict__ C, int N) {
  float4* r4 = (float4*)(C + (size_t)blockIdx.x * N);
  const int t = threadIdx.x;
  float4 v[4];
  float mx = -3.0e38f;
#pragma unroll
  for (int i = 0; i < 4; ++i) {
    v[i] = r4[t + i * 256];
    mx = fmaxf(mx, fmaxf(fmaxf(v[i].x, v[i].y), fmaxf(v[i].z, v[i].w)));
  }
#pragma unroll
  for (int o = 32; o; o >>= 1) mx = fmaxf(mx, __shfl_xor(mx, o, 64));
  __shared__ float smax[4], ssum[4];
  const int w = t >> 6;
  if ((t & 63) == 0) smax[w] = mx;
  __syncthreads();
  mx = fmaxf(fmaxf(smax[0], smax[1]), fmaxf(smax[2], smax[3]));
  float s = 0.f;
#pragma unroll
  for (int i = 0; i < 4; ++i) {
    v[i].x = __expf(v[i].x - mx);
    v[i].y = __expf(v[i].y - mx);
    v[i].z = __expf(v[i].z - mx);
    v[i].w = __expf(v[i].w - mx);
    s += (v[i].x + v[i].y) + (v[i].z + v[i].w);
  }
#pragma unroll
  for (int o = 32; o; o >>= 1) s += __shfl_xor(s, o, 64);
  if ((t & 63) == 0) ssum[w] = s;
  __syncthreads();
  const float inv = 1.0f / (ssum[0] + ssum[1] + ssum[2] + ssum[3]);
#pragma unroll
  for (int i = 0; i < 4; ++i) {
    v[i].x *= inv; v[i].y *= inv; v[i].z *= inv; v[i].w *= inv;
    r4[t + i * 256] = v[i];
  }
}

extern "C" void kernel_launch(void* const* d_in, const int* in_sizes, int n_in,
                              void* d_out, int out_size, void* d_ws, size_t ws_size,
                              hipStream_t stream) {
  const float* out_state = (const float*)d_in[0];  // [4096,1024]
  const float* history   = (const float*)d_in[1];  // [4096,1024]
  const float* W         = (const float*)d_in[2];  // [1024,1024]
  float* out = (float*)d_out;                      // [4096,4096]

  unsigned short* Hh = (unsigned short*)d_ws;                 // 4096x1024 each
  unsigned short* Hl = Hh + (size_t)4096 * 1024;
  unsigned short* Wh = Hl + (size_t)4096 * 1024;              // 1024x1024
  unsigned short* Wl = Wh + (size_t)1024 * 1024;
  unsigned short* Ah = Wl + (size_t)1024 * 1024;              // 4096x1024
  unsigned short* Al = Ah + (size_t)4096 * 1024;
  unsigned short* Ph = Al + (size_t)4096 * 1024;              // 4096x1024
  unsigned short* Pl = Ph + (size_t)4096 * 1024;
  float* P32 = (float*)(Pl + (size_t)4096 * 1024);            // 2 x 4096x1024 fp32

  split_kernel<<<4096, 256, 0, stream>>>(history, Hh, Hl);
  split_kernel<<<1024, 256, 0, stream>>>(W, Wh, Wl);
  split_kernel<<<4096, 256, 0, stream>>>(out_state, Ah, Al);

  // stage-1: split-K proj. 512 blocks (2 K-halves), 2 blocks/CU.
  gemm_p<<<512, 512, 0, stream>>>(Hh, Hl, Wh, Wl, P32);
  reduce_split<<<4096, 256, 0, stream>>>(P32, P32 + (size_t)4096 * 1024, Ph, Pl);

  // stage-2: energies. R15-exact 5-window lockstep, 256 blocks.
  gemm_e<<<256, 512, 0, stream>>>(Ah, Al, Ph, Pl, out);

  softmax_inplace<<<4096, 256, 0, stream>>>(out, 4096);
}